// Round 1
// baseline (381.742 us; speedup 1.0000x reference)
//
#include <hip/hip_runtime.h>
#include <hip/hip_bf16.h>
#include <stdint.h>

#define B_   16
#define C_   256
#define H_   64
#define W_   64
#define PH   66
#define PW   66
#define K1   2304   // 256*9
#define NO1  256
#define NO2  128

typedef unsigned short u16;
typedef __bf16 bf16x8 __attribute__((ext_vector_type(8)));
typedef float  f32x4  __attribute__((ext_vector_type(4)));

__device__ __forceinline__ void gl_lds16(const void* src, void* dst) {
    __builtin_amdgcn_global_load_lds(
        (const __attribute__((address_space(1))) unsigned int*)src,
        (__attribute__((address_space(3))) unsigned int*)dst, 16, 0, 0);
}

__device__ __forceinline__ u16 sign_bf16(float v) {
    return (v > 0.f) ? (u16)0x3F80 : ((v < 0.f) ? (u16)0xBF80 : (u16)0);
}

// ---------------- halo zero: zero the 1-px border of s1 and s2 ----------------
__global__ void halo_zero(u16* __restrict__ s1, u16* __restrict__ s2) {
    int t = blockIdx.x * blockDim.x + threadIdx.x;   // one thread = 8 channels of one pixel
    const int total = B_ * PH * PW * (C_ / 8);
    if (t >= total) return;
    int pix = t >> 5;          // C_/8 = 32
    int c8  = t & 31;
    int pw  = pix % PW;
    int ph  = (pix / PW) % PH;
    if (ph != 0 && ph != PH - 1 && pw != 0 && pw != PW - 1) return;
    int4 z = make_int4(0, 0, 0, 0);
    *(int4*)(s1 + (size_t)pix * C_ + c8 * 8) = z;
    *(int4*)(s2 + (size_t)pix * C_ + c8 * 8) = z;
}

// ---------------- prep s1: sign(x + bias1_) -> padded NHWC bf16 ----------------
__global__ void prep_s1(const float* __restrict__ x, const float* __restrict__ bias1_,
                        u16* __restrict__ s1) {
    __shared__ u16 tile[64][260];          // [w][c], pad to kill bank conflicts
    int b = blockIdx.x >> 6;
    int h = blockIdx.x & 63;
    int t = threadIdx.x;
    int w  = t & 63;
    int cq = t >> 6;                       // 0..3
    for (int i = 0; i < 64; ++i) {
        int c = i * 4 + cq;
        float v = x[((size_t)(b * C_ + c) * H_ + h) * W_ + w] + bias1_[c];
        tile[w][c] = sign_bf16(v);
    }
    __syncthreads();
    int lane32 = t & 31;
    int grp    = t >> 5;                   // 0..7
    for (int i = 0; i < 8; ++i) {
        int w2 = i * 8 + grp;
        ushort4 v0 = *(const ushort4*)&tile[w2][lane32 * 8];
        ushort4 v1 = *(const ushort4*)&tile[w2][lane32 * 8 + 4];
        u16* dst = s1 + ((size_t)(b * PH + h + 1) * PW + (w2 + 1)) * C_ + lane32 * 8;
        *(ushort4*)dst       = v0;
        *(ushort4*)(dst + 4) = v1;
    }
}

// ---------------- prep weights: scale[o] and sign(w) transposed to [n][k] ------
// k ordering: k = tap*256 + c   (tap = dh*3+dw)
__global__ void prep_w(const float* __restrict__ w1, const float* __restrict__ w2,
                       const float* __restrict__ ka1, const float* __restrict__ kw1,
                       const float* __restrict__ ka2, const float* __restrict__ kw2,
                       u16* __restrict__ Bt1, u16* __restrict__ Bt2,
                       float* __restrict__ scale1, float* __restrict__ scale2) {
    int o = blockIdx.x;
    const float* w; u16* Bt; float* scale; float kk;
    if (o < NO1) { w = w1 + (size_t)o * K1;         Bt = Bt1 + (size_t)o * K1;         scale = scale1 + o;         kk = ka1[0] * kw1[0]; }
    else         { int oo = o - NO1;
                   w = w2 + (size_t)oo * K1;        Bt = Bt2 + (size_t)oo * K1;        scale = scale2 + oo;        kk = ka2[0] * kw2[0]; }
    int t = threadIdx.x;
    float s = 0.f;
    for (int e = t; e < K1; e += 256) {
        float v = w[e];
        s += fabsf(v);
        int c = e / 9, tap = e % 9;
        Bt[tap * 256 + c] = sign_bf16(v);
    }
    for (int off = 32; off; off >>= 1) s += __shfl_down(s, off);
    __shared__ float red[4];
    if ((t & 63) == 0) red[t >> 6] = s;
    __syncthreads();
    if (t == 0) {
        float tot = red[0] + red[1] + red[2] + red[3];
        *scale = kk * tot * (1.0f / 2304.0f);
    }
}

// ---------------- implicit-GEMM binary conv, 128x128 tile, BK=64 ----------------
// A: padded-NHWC sign tensor Sin [B][66][66][256]; M row = (b, h0+hh, w)
// B: Bt [NO][2304] (k contiguous)
// EPI==1: conv1 epilogue (xres = v + x; write sign(xres+bias2_) to s2out, xres[:,:128] to xres_out NHWC)
// EPI==2: conv2 epilogue (v + xres + bias3 -> prelu -> +bias4 -> pixel_unshuffle into dout)
template<int EPI>
__global__ __launch_bounds__(256)
void gemm_conv(const u16* __restrict__ Sin, const u16* __restrict__ Bt,
               const float* __restrict__ scale,
               const float* __restrict__ xaux,    // EPI1: x (NCHW f32); EPI2: xres_lo (NHWC 128 f32)
               const float* __restrict__ biasA,   // EPI1: bias2_ ; EPI2: bias3
               const float* __restrict__ bias4,   // EPI2 only
               const float* __restrict__ slope,   // EPI2 only
               u16*  __restrict__ s2out,          // EPI1 only
               float* __restrict__ xres_out,      // EPI1 only
               float* __restrict__ dout)          // EPI2 only
{
    __shared__ char lds[32 * 1024];
    char* As = lds;                // [128 rows][128 B]  (row = m, 64 bf16 of k)
    char* Bs = lds + 16 * 1024;    // [128 rows][128 B]  (row = n, 64 bf16 of k)

    int t  = threadIdx.x;
    int mb = blockIdx.x;           // 0..511 : (b, h2)
    int nb = blockIdx.y;
    int b  = mb >> 5;
    int h0 = (mb & 31) * 2;        // rows h0, h0+1

    int ar  = t >> 3;              // staging row 0..31 (+i*32)
    int ac8 = (t & 7) * 8;         // element offset within row (8 bf16 = 16B)

    int l  = t & 63;
    int wv = t >> 6;
    int wr = wv >> 1;              // wave M half
    int wc = wv & 1;               // wave N half

    f32x4 acc[4][4];
#pragma unroll
    for (int mi = 0; mi < 4; ++mi)
#pragma unroll
        for (int ni = 0; ni < 4; ++ni) acc[mi][ni] = (f32x4){0.f, 0.f, 0.f, 0.f};

    for (int ks = 0; ks < 36; ++ks) {
        int tap = ks >> 2;
        int c0  = (ks & 3) * 64;
        int dh  = tap / 3, dw = tap % 3;
#pragma unroll
        for (int i = 0; i < 4; ++i) {
            int r  = ar + i * 32;
            int hh = r >> 6, ww = r & 63;
            const u16* ga = Sin + ((size_t)(b * PH + h0 + hh + dh) * PW + (ww + dw)) * C_ + c0 + ac8;
            gl_lds16(ga, As + r * 128 + ac8 * 2);
        }
#pragma unroll
        for (int i = 0; i < 4; ++i) {
            int r = ar + i * 32;
            int n = nb * 128 + r;
            const u16* gb = Bt + (size_t)n * K1 + tap * 256 + c0 + ac8;
            gl_lds16(gb, Bs + r * 128 + ac8 * 2);
        }
        __syncthreads();
#pragma unroll
        for (int kk = 0; kk < 2; ++kk) {
            int kb = kk * 64 + ((l >> 4) * 16);   // byte offset of this lane's k-group
            bf16x8 af[4], bf[4];
#pragma unroll
            for (int mi = 0; mi < 4; ++mi)
                af[mi] = *(const bf16x8*)(As + (wr * 64 + mi * 16 + (l & 15)) * 128 + kb);
#pragma unroll
            for (int ni = 0; ni < 4; ++ni)
                bf[ni] = *(const bf16x8*)(Bs + (wc * 64 + ni * 16 + (l & 15)) * 128 + kb);
#pragma unroll
            for (int mi = 0; mi < 4; ++mi)
#pragma unroll
                for (int ni = 0; ni < 4; ++ni)
                    acc[mi][ni] = __builtin_amdgcn_mfma_f32_16x16x32_bf16(af[mi], bf[ni], acc[mi][ni], 0, 0, 0);
        }
        __syncthreads();
    }

    // -------- epilogue --------
    int co = l & 15;
    int ro = l >> 4;
#pragma unroll
    for (int mi = 0; mi < 4; ++mi) {
#pragma unroll
        for (int ni = 0; ni < 4; ++ni) {
            int n_loc = wc * 64 + ni * 16 + co;
            int o = nb * 128 + n_loc;
            float sc = scale[o];
#pragma unroll
            for (int j = 0; j < 4; ++j) {
                int m_loc = wr * 64 + mi * 16 + ro * 4 + j;
                int h = h0 + (m_loc >> 6);
                int w = m_loc & 63;
                float v = acc[mi][ni][j] * sc;
                if (EPI == 1) {
                    float xv = xaux[((size_t)(b * C_ + o) * H_ + h) * W_ + w];
                    float xr = v + xv;
                    float sv = xr + biasA[o];
                    s2out[((size_t)(b * PH + h + 1) * PW + (w + 1)) * C_ + o] = sign_bf16(sv);
                    if (o < NO2)
                        xres_out[(((size_t)b * H_ + h) * W_ + w) * NO2 + o] = xr;
                } else {
                    float xr = xaux[(((size_t)b * H_ + h) * W_ + w) * NO2 + o];
                    float vv = v + xr + biasA[o];
                    vv = (vv >= 0.f) ? vv : vv * slope[o];
                    vv += bias4[o];
                    int p = h & 1, q = w & 1;
                    dout[(((size_t)b * 512 + (o * 4 + p * 2 + q)) * 32 + (h >> 1)) * 32 + (w >> 1)] = vv;
                }
            }
        }
    }
}

// ---------------- workspace layout (bytes, 256-aligned) ----------------
static const size_t SZ_S1  = (size_t)B_ * PH * PW * C_ * 2;      // 35,684,352
static const size_t OFF_S1 = 0;
static const size_t OFF_S2 = OFF_S1 + SZ_S1;
static const size_t OFF_B1 = OFF_S2 + SZ_S1;                      // 71,368,704
static const size_t OFF_B2 = OFF_B1 + (size_t)NO1 * K1 * 2;       // +1,179,648
static const size_t OFF_C1 = OFF_B2 + (size_t)NO2 * K1 * 2;       // +589,824
static const size_t OFF_C2 = OFF_C1 + 1024;
static const size_t OFF_XR = OFF_C2 + 512;                        // 73,139,712 (256-aligned)

extern "C" void kernel_launch(void* const* d_in, const int* in_sizes, int n_in,
                              void* d_out, int out_size, void* d_ws, size_t ws_size,
                              hipStream_t stream) {
    (void)in_sizes; (void)n_in; (void)out_size; (void)ws_size;
    const float* x      = (const float*)d_in[0];
    const float* w1     = (const float*)d_in[1];
    const float* w2     = (const float*)d_in[2];
    const float* bias1_ = (const float*)d_in[3];
    const float* bias2_ = (const float*)d_in[6];
    const float* bias3  = (const float*)d_in[7];
    const float* bias4  = (const float*)d_in[8];
    const float* ka1    = (const float*)d_in[9];
    const float* kw1    = (const float*)d_in[10];
    const float* ka2    = (const float*)d_in[11];
    const float* kw2    = (const float*)d_in[12];
    const float* slope2 = (const float*)d_in[14];

    char* ws = (char*)d_ws;
    u16*   s1   = (u16*)(ws + OFF_S1);
    u16*   s2   = (u16*)(ws + OFF_S2);
    u16*   Bt1  = (u16*)(ws + OFF_B1);
    u16*   Bt2  = (u16*)(ws + OFF_B2);
    float* sc1  = (float*)(ws + OFF_C1);
    float* sc2  = (float*)(ws + OFF_C2);
    float* xres = (float*)(ws + OFF_XR);
    float* out  = (float*)d_out;

    {
        int total = B_ * PH * PW * (C_ / 8);
        hipLaunchKernelGGL(halo_zero, dim3((total + 255) / 256), dim3(256), 0, stream, s1, s2);
    }
    hipLaunchKernelGGL(prep_s1, dim3(B_ * H_), dim3(256), 0, stream, x, bias1_, s1);
    hipLaunchKernelGGL(prep_w, dim3(NO1 + NO2), dim3(256), 0, stream,
                       w1, w2, ka1, kw1, ka2, kw2, Bt1, Bt2, sc1, sc2);
    hipLaunchKernelGGL((gemm_conv<1>), dim3(512, 2), dim3(256), 0, stream,
                       s1, Bt1, sc1, x, bias2_, nullptr, nullptr, s2, xres, nullptr);
    hipLaunchKernelGGL((gemm_conv<2>), dim3(512, 1), dim3(256), 0, stream,
                       s2, Bt2, sc2, xres, bias3, bias4, slope2, nullptr, nullptr, out);
}

// Round 5
// 347.668 us; speedup vs baseline: 1.0980x; 1.0980x over previous
//
#include <hip/hip_runtime.h>
#include <hip/hip_bf16.h>
#include <stdint.h>

#define B_   16
#define C_   256
#define H_   64
#define W_   64
#define PH   66
#define PW   66
#define K1   2304   // 256*9
#define NO1  256
#define NO2  128

typedef unsigned short u16;
typedef __bf16 bf16x8 __attribute__((ext_vector_type(8)));
typedef float  f32x4  __attribute__((ext_vector_type(4)));

__device__ __forceinline__ void gl_lds16(const void* src, void* dst) {
    __builtin_amdgcn_global_load_lds(
        (const __attribute__((address_space(1))) unsigned int*)src,
        (__attribute__((address_space(3))) unsigned int*)dst, 16, 0, 0);
}

__device__ __forceinline__ u16 sign_bf16(float v) {
    return (v > 0.f) ? (u16)0x3F80 : ((v < 0.f) ? (u16)0xBF80 : (u16)0);
}

// ---------------- halo zero: zero the 1-px border of s1 and s2 ----------------
__global__ void halo_zero(u16* __restrict__ s1, u16* __restrict__ s2) {
    int t = blockIdx.x * blockDim.x + threadIdx.x;   // one thread = 8 channels of one pixel
    const int total = B_ * PH * PW * (C_ / 8);
    if (t >= total) return;
    int pix = t >> 5;          // C_/8 = 32
    int c8  = t & 31;
    int pw  = pix % PW;
    int ph  = (pix / PW) % PH;
    if (ph != 0 && ph != PH - 1 && pw != 0 && pw != PW - 1) return;
    int4 z = make_int4(0, 0, 0, 0);
    *(int4*)(s1 + (size_t)pix * C_ + c8 * 8) = z;
    *(int4*)(s2 + (size_t)pix * C_ + c8 * 8) = z;
}

// ---------------- prep s1: sign(x + bias1_) -> padded NHWC bf16 ----------------
__global__ void prep_s1(const float* __restrict__ x, const float* __restrict__ bias1_,
                        u16* __restrict__ s1) {
    __shared__ u16 tile[64][260];          // [w][c], pad to kill bank conflicts
    int b = blockIdx.x >> 6;
    int h = blockIdx.x & 63;
    int t = threadIdx.x;
    int w  = t & 63;
    int cq = t >> 6;                       // 0..3
    for (int i = 0; i < 64; ++i) {
        int c = i * 4 + cq;
        float v = x[((size_t)(b * C_ + c) * H_ + h) * W_ + w] + bias1_[c];
        tile[w][c] = sign_bf16(v);
    }
    __syncthreads();
    int lane32 = t & 31;
    int grp    = t >> 5;                   // 0..7
    for (int i = 0; i < 8; ++i) {
        int w2 = i * 8 + grp;
        ushort4 v0 = *(const ushort4*)&tile[w2][lane32 * 8];
        ushort4 v1 = *(const ushort4*)&tile[w2][lane32 * 8 + 4];
        u16* dst = s1 + ((size_t)(b * PH + h + 1) * PW + (w2 + 1)) * C_ + lane32 * 8;
        *(ushort4*)dst       = v0;
        *(ushort4*)(dst + 4) = v1;
    }
}

// ---------------- prep weights: scale[o] and sign(w) transposed to [n][k] ------
// k ordering: k = tap*256 + c   (tap = dh*3+dw)
__global__ void prep_w(const float* __restrict__ w1, const float* __restrict__ w2,
                       const float* __restrict__ ka1, const float* __restrict__ kw1,
                       const float* __restrict__ ka2, const float* __restrict__ kw2,
                       u16* __restrict__ Bt1, u16* __restrict__ Bt2,
                       float* __restrict__ scale1, float* __restrict__ scale2) {
    int o = blockIdx.x;
    const float* w; u16* Bt; float* scale; float kk;
    if (o < NO1) { w = w1 + (size_t)o * K1;         Bt = Bt1 + (size_t)o * K1;         scale = scale1 + o;         kk = ka1[0] * kw1[0]; }
    else         { int oo = o - NO1;
                   w = w2 + (size_t)oo * K1;        Bt = Bt2 + (size_t)oo * K1;        scale = scale2 + oo;        kk = ka2[0] * kw2[0]; }
    int t = threadIdx.x;
    float s = 0.f;
    for (int e = t; e < K1; e += 256) {
        float v = w[e];
        s += fabsf(v);
        int c = e / 9, tap = e % 9;
        Bt[tap * 256 + c] = sign_bf16(v);
    }
    for (int off = 32; off; off >>= 1) s += __shfl_down(s, off);
    __shared__ float red[4];
    if ((t & 63) == 0) red[t >> 6] = s;
    __syncthreads();
    if (t == 0) {
        float tot = red[0] + red[1] + red[2] + red[3];
        *scale = kk * tot * (1.0f / 2304.0f);
    }
}

// ---------------- implicit-GEMM binary conv, 128x128 tile, BK=64 ----------------
// A: padded-NHWC sign tensor Sin [B][66][66][256]; M row = (b, h0+hh, w)
// B: Bt [NO][2304] (k contiguous)
// LDS layout: linear dst for global_load_lds; logical byte col cb of row r lives
// at cb ^ ((r&7)<<4)  (T2 st-swizzle, both-sides: pre-swizzled global source +
// swizzled ds_read — rule #21).
// EPI==1: conv1 epilogue (xres = v + x; write sign(xres+bias2_) to s2out, xres[:,:128] to xres_out NHWC)
// EPI==2: conv2 epilogue (v + xres + bias3 -> prelu -> +bias4 -> pixel_unshuffle into dout)
template<int EPI>
__global__ __launch_bounds__(256)
void gemm_conv(const u16* __restrict__ Sin, const u16* __restrict__ Bt,
               const float* __restrict__ scale,
               const float* __restrict__ xaux,    // EPI1: x (NCHW f32); EPI2: xres_lo (NHWC 128 f32)
               const float* __restrict__ biasA,   // EPI1: bias2_ ; EPI2: bias3
               const float* __restrict__ bias4,   // EPI2 only
               const float* __restrict__ slope,   // EPI2 only
               u16*  __restrict__ s2out,          // EPI1 only
               float* __restrict__ xres_out,      // EPI1 only
               float* __restrict__ dout)          // EPI2 only
{
    __shared__ char lds[32 * 1024];
    char* As = lds;                // [128 rows][128 B]  (row = m, 64 bf16 of k)
    char* Bs = lds + 16 * 1024;    // [128 rows][128 B]  (row = n, 64 bf16 of k)

    int t  = threadIdx.x;

    // 1D grid + XCD chunk swizzle (T1): nwg % 8 == 0 -> bijective.
    int wg    = blockIdx.x;
    int chunk = gridDim.x >> 3;
    int logical = (wg & 7) * chunk + (wg >> 3);
    int nb, mb;
    if (EPI == 1) { nb = logical & 1; mb = logical >> 1; }   // nb fastest: A-tile reuse
    else          { nb = 0;           mb = logical; }
    int b  = mb >> 5;
    int h0 = (mb & 31) * 2;        // rows h0, h0+1

    int ar  = t >> 3;              // staging row 0..31 (+i*32)
    int swz = ((t >> 3) & 7) << 3; // element-xor for pre-swizzled global source
    int ac8 = ((t & 7) * 8) ^ swz; // swizzled element offset within 64-elem row chunk

    int l  = t & 63;
    int wv = t >> 6;
    int wr = wv >> 1;              // wave M half
    int wc = wv & 1;               // wave N half

    f32x4 acc[4][4];
#pragma unroll
    for (int mi = 0; mi < 4; ++mi)
#pragma unroll
        for (int ni = 0; ni < 4; ++ni) acc[mi][ni] = (f32x4){0.f, 0.f, 0.f, 0.f};

    for (int ks = 0; ks < 36; ++ks) {
        int tap = ks >> 2;
        int c0  = (ks & 3) * 64;
        int dh  = tap / 3, dw = tap % 3;
#pragma unroll
        for (int i = 0; i < 4; ++i) {
            int r  = ar + i * 32;
            int hh = r >> 6, ww = r & 63;
            const u16* ga = Sin + ((size_t)(b * PH + h0 + hh + dh) * PW + (ww + dw)) * C_ + c0 + ac8;
            gl_lds16(ga, As + r * 128 + ((t & 7) * 16));
        }
#pragma unroll
        for (int i = 0; i < 4; ++i) {
            int r = ar + i * 32;
            int n = nb * 128 + r;
            const u16* gb = Bt + (size_t)n * K1 + tap * 256 + c0 + ac8;
            gl_lds16(gb, Bs + r * 128 + ((t & 7) * 16));
        }
        __syncthreads();
#pragma unroll
        for (int kk = 0; kk < 2; ++kk) {
            int kb = kk * 64 + ((l >> 4) * 16);   // logical byte offset of this lane's k-group
            int rx = (l & 7) << 4;                // row-dependent xor (row&7 == l&7 here)
            bf16x8 af[4], bf[4];
#pragma unroll
            for (int mi = 0; mi < 4; ++mi)
                af[mi] = *(const bf16x8*)(As + (wr * 64 + mi * 16 + (l & 15)) * 128 + (kb ^ rx));
#pragma unroll
            for (int ni = 0; ni < 4; ++ni)
                bf[ni] = *(const bf16x8*)(Bs + (wc * 64 + ni * 16 + (l & 15)) * 128 + (kb ^ rx));
#pragma unroll
            for (int mi = 0; mi < 4; ++mi)
#pragma unroll
                for (int ni = 0; ni < 4; ++ni)
                    acc[mi][ni] = __builtin_amdgcn_mfma_f32_16x16x32_bf16(af[mi], bf[ni], acc[mi][ni], 0, 0, 0);
        }
        __syncthreads();
    }

    // -------- epilogue --------
    int co = l & 15;
    int ro = l >> 4;
#pragma unroll
    for (int mi = 0; mi < 4; ++mi) {
#pragma unroll
        for (int ni = 0; ni < 4; ++ni) {
            int n_loc = wc * 64 + ni * 16 + co;
            int o = nb * 128 + n_loc;
            float sc = scale[o];
#pragma unroll
            for (int j = 0; j < 4; ++j) {
                int m_loc = wr * 64 + mi * 16 + ro * 4 + j;
                int h = h0 + (m_loc >> 6);
                int w = m_loc & 63;
                float v = acc[mi][ni][j] * sc;
                if (EPI == 1) {
                    float xv = xaux[((size_t)(b * C_ + o) * H_ + h) * W_ + w];
                    float xr = v + xv;
                    float sv = xr + biasA[o];
                    s2out[((size_t)(b * PH + h + 1) * PW + (w + 1)) * C_ + o] = sign_bf16(sv);
                    if (o < NO2)
                        xres_out[(((size_t)b * H_ + h) * W_ + w) * NO2 + o] = xr;
                } else {
                    float xr = xaux[(((size_t)b * H_ + h) * W_ + w) * NO2 + o];
                    float vv = v + xr + biasA[o];
                    vv = (vv >= 0.f) ? vv : vv * slope[o];
                    vv += bias4[o];
                    int p = h & 1, q = w & 1;
                    dout[(((size_t)b * 512 + (o * 4 + p * 2 + q)) * 32 + (h >> 1)) * 32 + (w >> 1)] = vv;
                }
            }
        }
    }
}

// ---------------- workspace layout (bytes, 256-aligned) ----------------
static const size_t SZ_S1  = (size_t)B_ * PH * PW * C_ * 2;      // 35,684,352
static const size_t OFF_S1 = 0;
static const size_t OFF_S2 = OFF_S1 + SZ_S1;
static const size_t OFF_B1 = OFF_S2 + SZ_S1;                      // 71,368,704
static const size_t OFF_B2 = OFF_B1 + (size_t)NO1 * K1 * 2;       // +1,179,648
static const size_t OFF_C1 = OFF_B2 + (size_t)NO2 * K1 * 2;       // +589,824
static const size_t OFF_C2 = OFF_C1 + 1024;
static const size_t OFF_XR = OFF_C2 + 512;                        // 73,139,712 (256-aligned)

extern "C" void kernel_launch(void* const* d_in, const int* in_sizes, int n_in,
                              void* d_out, int out_size, void* d_ws, size_t ws_size,
                              hipStream_t stream) {
    (void)in_sizes; (void)n_in; (void)out_size; (void)ws_size;
    const float* x      = (const float*)d_in[0];
    const float* w1     = (const float*)d_in[1];
    const float* w2     = (const float*)d_in[2];
    const float* bias1_ = (const float*)d_in[3];
    const float* bias2_ = (const float*)d_in[6];
    const float* bias3  = (const float*)d_in[7];
    const float* bias4  = (const float*)d_in[8];
    const float* ka1    = (const float*)d_in[9];
    const float* kw1    = (const float*)d_in[10];
    const float* ka2    = (const float*)d_in[11];
    const float* kw2    = (const float*)d_in[12];
    const float* slope2 = (const float*)d_in[14];

    char* ws = (char*)d_ws;
    u16*   s1   = (u16*)(ws + OFF_S1);
    u16*   s2   = (u16*)(ws + OFF_S2);
    u16*   Bt1  = (u16*)(ws + OFF_B1);
    u16*   Bt2  = (u16*)(ws + OFF_B2);
    float* sc1  = (float*)(ws + OFF_C1);
    float* sc2  = (float*)(ws + OFF_C2);
    float* xres = (float*)(ws + OFF_XR);
    float* out  = (float*)d_out;

    {
        int total = B_ * PH * PW * (C_ / 8);
        hipLaunchKernelGGL(halo_zero, dim3((total + 255) / 256), dim3(256), 0, stream, s1, s2);
    }
    hipLaunchKernelGGL(prep_s1, dim3(B_ * H_), dim3(256), 0, stream, x, bias1_, s1);
    hipLaunchKernelGGL(prep_w, dim3(NO1 + NO2), dim3(256), 0, stream,
                       w1, w2, ka1, kw1, ka2, kw2, Bt1, Bt2, sc1, sc2);
    hipLaunchKernelGGL((gemm_conv<1>), dim3(1024), dim3(256), 0, stream,
                       s1, Bt1, sc1, x, bias2_, nullptr, nullptr, s2, xres, nullptr);
    hipLaunchKernelGGL((gemm_conv<2>), dim3(512), dim3(256), 0, stream,
                       s2, Bt2, sc2, xres, bias3, bias4, slope2, nullptr, nullptr, out);
}

// Round 6
// 278.267 us; speedup vs baseline: 1.3719x; 1.2494x over previous
//
#include <hip/hip_runtime.h>
#include <hip/hip_bf16.h>
#include <stdint.h>

#define B_   16
#define C_   256
#define H_   64
#define W_   64
#define PH   66
#define PW   66
#define K1   2304   // 256*9
#define NO1  256
#define NO2  128

typedef unsigned short u16;
typedef signed char i8;
typedef int   int32x4 __attribute__((ext_vector_type(4)));

__device__ __forceinline__ void gl_lds16(const void* src, void* dst) {
    __builtin_amdgcn_global_load_lds(
        (const __attribute__((address_space(1))) unsigned int*)src,
        (__attribute__((address_space(3))) unsigned int*)dst, 16, 0, 0);
}

__device__ __forceinline__ i8 sign_i8(float v) {
    return (v > 0.f) ? (i8)1 : ((v < 0.f) ? (i8)(-1) : (i8)0);
}

// ---------------- halo zero: zero the 1-px border of s1 and s2 (i8) -----------
__global__ void halo_zero(i8* __restrict__ s1, i8* __restrict__ s2) {
    int t = blockIdx.x * blockDim.x + threadIdx.x;   // one thread = 16 channels of one pixel
    const int total = B_ * PH * PW * (C_ / 16);
    if (t >= total) return;
    int pix = t >> 4;          // C_/16 = 16 chunks
    int c16 = t & 15;
    int pw  = pix % PW;
    int ph  = (pix / PW) % PH;
    if (ph != 0 && ph != PH - 1 && pw != 0 && pw != PW - 1) return;
    int4 z = make_int4(0, 0, 0, 0);
    *(int4*)(s1 + (size_t)pix * C_ + c16 * 16) = z;
    *(int4*)(s2 + (size_t)pix * C_ + c16 * 16) = z;
}

// ---------------- prep s1: sign(x + bias1_) -> padded NHWC i8 ----------------
__global__ void prep_s1(const float* __restrict__ x, const float* __restrict__ bias1_,
                        i8* __restrict__ s1) {
    __shared__ i8 tile[64][272];           // [w][c], stride 272 (17*16) to spread banks
    int b = blockIdx.x >> 6;
    int h = blockIdx.x & 63;
    int t = threadIdx.x;
    int w  = t & 63;
    int cq = t >> 6;                       // 0..3 (channel quarter)
    for (int i = 0; i < 64; ++i) {
        int c = cq * 64 + i;
        float v = x[((size_t)(b * C_ + c) * H_ + h) * W_ + w] + bias1_[c];
        tile[w][c] = sign_i8(v);
    }
    __syncthreads();
    // write out: 1024 16B-chunks, 4 per thread, consecutive t -> consecutive channels
    for (int i = 0; i < 4; ++i) {
        int idx = i * 256 + t;
        int w2  = idx >> 4;                // 16 chunks per pixel
        int cb  = (idx & 15) * 16;
        int4 v = *(const int4*)&tile[w2][cb];
        *(int4*)(s1 + ((size_t)(b * PH + h + 1) * PW + (w2 + 1)) * C_ + cb) = v;
    }
}

// ---------------- prep weights: scale[o] and sign(w) transposed to [n][k] ------
// k ordering: k = tap*256 + c   (tap = dh*3+dw)
__global__ void prep_w(const float* __restrict__ w1, const float* __restrict__ w2,
                       const float* __restrict__ ka1, const float* __restrict__ kw1,
                       const float* __restrict__ ka2, const float* __restrict__ kw2,
                       i8* __restrict__ Bt1, i8* __restrict__ Bt2,
                       float* __restrict__ scale1, float* __restrict__ scale2) {
    int o = blockIdx.x;
    const float* w; i8* Bt; float* scale; float kk;
    if (o < NO1) { w = w1 + (size_t)o * K1;         Bt = Bt1 + (size_t)o * K1;         scale = scale1 + o;         kk = ka1[0] * kw1[0]; }
    else         { int oo = o - NO1;
                   w = w2 + (size_t)oo * K1;        Bt = Bt2 + (size_t)oo * K1;        scale = scale2 + oo;        kk = ka2[0] * kw2[0]; }
    int t = threadIdx.x;
    float s = 0.f;
    for (int e = t; e < K1; e += 256) {
        float v = w[e];
        s += fabsf(v);
        int c = e / 9, tap = e % 9;
        Bt[tap * 256 + c] = sign_i8(v);
    }
    for (int off = 32; off; off >>= 1) s += __shfl_down(s, off);
    __shared__ float red[4];
    if ((t & 63) == 0) red[t >> 6] = s;
    __syncthreads();
    if (t == 0) {
        float tot = red[0] + red[1] + red[2] + red[3];
        *scale = kk * tot * (1.0f / 2304.0f);
    }
}

// ---------------- implicit-GEMM binary conv, i8 path, 128x128 tile, BK=128 -----
// A: padded-NHWC sign tensor Sin [B][66][66][256] i8; M row = (b, h0+hh, w)
// B: Bt [NO][2304] i8 (k contiguous)
// mfma_i32_16x16x64_i8: exact {-1,0,1} dot products in i32; 2x bf16 rate,
// half the staging bytes -> 18 K-steps of BK=128 in the same 128B-row LDS
// geometry (T2 XOR swizzle unchanged: byte col cb of row r lives at
// cb ^ ((r&7)<<4); linear LDS dst + pre-swizzled global source, rule #21).
// EPI==1: conv1 epilogue (xres = v + x; sign(xres+bias2_) -> s2out, xres[:,:128] -> xres_out NHWC)
// EPI==2: conv2 epilogue (v + xres + bias3 -> prelu -> +bias4 -> pixel_unshuffle into dout)
template<int EPI>
__global__ __launch_bounds__(256)
void gemm_conv(const i8* __restrict__ Sin, const i8* __restrict__ Bt,
               const float* __restrict__ scale,
               const float* __restrict__ xaux,    // EPI1: x (NCHW f32); EPI2: xres_lo (NHWC 128 f32)
               const float* __restrict__ biasA,   // EPI1: bias2_ ; EPI2: bias3
               const float* __restrict__ bias4,   // EPI2 only
               const float* __restrict__ slope,   // EPI2 only
               i8*   __restrict__ s2out,          // EPI1 only
               float* __restrict__ xres_out,      // EPI1 only
               float* __restrict__ dout)          // EPI2 only
{
    __shared__ char lds[32 * 1024];
    char* As = lds;                // [128 rows][128 B] (row = m, 128 i8 of k)
    char* Bs = lds + 16 * 1024;    // [128 rows][128 B] (row = n, 128 i8 of k)

    int t  = threadIdx.x;

    // 1D grid + XCD chunk swizzle (T1): nwg % 8 == 0 -> bijective.
    int wg    = blockIdx.x;
    int chunk = gridDim.x >> 3;
    int logical = (wg & 7) * chunk + (wg >> 3);
    int nb, mb;
    if (EPI == 1) { nb = logical & 1; mb = logical >> 1; }   // nb fastest: A-tile reuse
    else          { nb = 0;           mb = logical; }
    int b  = mb >> 5;
    int h0 = (mb & 31) * 2;        // rows h0, h0+1

    int ar  = t >> 3;              // staging row 0..31 (+i*32); r&7 == (t>>3)&7
    // pre-swizzled global byte offset within the 128B k-row (involution with read side)
    int off = ((t & 7) * 16) ^ (((t >> 3) & 7) << 4);

    int l  = t & 63;
    int wv = t >> 6;
    int wr = wv >> 1;              // wave M half
    int wc = wv & 1;               // wave N half

    int32x4 acc[4][4];
#pragma unroll
    for (int mi = 0; mi < 4; ++mi)
#pragma unroll
        for (int ni = 0; ni < 4; ++ni) acc[mi][ni] = (int32x4){0, 0, 0, 0};

    for (int ks = 0; ks < 18; ++ks) {
        int tap = ks >> 1;
        int c0  = (ks & 1) * 128;
        int dh  = tap / 3, dw = tap % 3;
#pragma unroll
        for (int i = 0; i < 4; ++i) {
            int r  = ar + i * 32;
            int hh = r >> 6, ww = r & 63;
            const i8* ga = Sin + ((size_t)(b * PH + h0 + hh + dh) * PW + (ww + dw)) * C_ + c0 + off;
            gl_lds16(ga, As + r * 128 + ((t & 7) * 16));
        }
#pragma unroll
        for (int i = 0; i < 4; ++i) {
            int r = ar + i * 32;
            int n = nb * 128 + r;
            const i8* gb = Bt + (size_t)n * K1 + tap * 256 + c0 + off;
            gl_lds16(gb, Bs + r * 128 + ((t & 7) * 16));
        }
        __syncthreads();
#pragma unroll
        for (int kk = 0; kk < 2; ++kk) {
            int kb = kk * 64 + ((l >> 4) * 16);   // logical byte offset of this lane's k-group
            int rx = (l & 7) << 4;                // row-dependent xor (row&7 == l&7 here)
            int32x4 af[4], bf[4];
#pragma unroll
            for (int mi = 0; mi < 4; ++mi)
                af[mi] = *(const int32x4*)(As + (wr * 64 + mi * 16 + (l & 15)) * 128 + (kb ^ rx));
#pragma unroll
            for (int ni = 0; ni < 4; ++ni)
                bf[ni] = *(const int32x4*)(Bs + (wc * 64 + ni * 16 + (l & 15)) * 128 + (kb ^ rx));
#pragma unroll
            for (int mi = 0; mi < 4; ++mi)
#pragma unroll
                for (int ni = 0; ni < 4; ++ni)
                    acc[mi][ni] = __builtin_amdgcn_mfma_i32_16x16x64_i8(af[mi], bf[ni], acc[mi][ni], 0, 0, 0);
        }
        __syncthreads();
    }

    // -------- epilogue --------
    int co = l & 15;
    int ro = l >> 4;
#pragma unroll
    for (int mi = 0; mi < 4; ++mi) {
#pragma unroll
        for (int ni = 0; ni < 4; ++ni) {
            int n_loc = wc * 64 + ni * 16 + co;
            int o = nb * 128 + n_loc;
            float sc = scale[o];
#pragma unroll
            for (int j = 0; j < 4; ++j) {
                int m_loc = wr * 64 + mi * 16 + ro * 4 + j;
                int h = h0 + (m_loc >> 6);
                int w = m_loc & 63;
                float v = (float)acc[mi][ni][j] * sc;
                if (EPI == 1) {
                    float xv = xaux[((size_t)(b * C_ + o) * H_ + h) * W_ + w];
                    float xr = v + xv;
                    float sv = xr + biasA[o];
                    s2out[((size_t)(b * PH + h + 1) * PW + (w + 1)) * C_ + o] = sign_i8(sv);
                    if (o < NO2)
                        xres_out[(((size_t)b * H_ + h) * W_ + w) * NO2 + o] = xr;
                } else {
                    float xr = xaux[(((size_t)b * H_ + h) * W_ + w) * NO2 + o];
                    float vv = v + xr + biasA[o];
                    vv = (vv >= 0.f) ? vv : vv * slope[o];
                    vv += bias4[o];
                    int p = h & 1, q = w & 1;
                    dout[(((size_t)b * 512 + (o * 4 + p * 2 + q)) * 32 + (h >> 1)) * 32 + (w >> 1)] = vv;
                }
            }
        }
    }
}

// ---------------- workspace layout (bytes, 256-aligned) ----------------
static const size_t SZ_S   = (size_t)B_ * PH * PW * C_;           // 17,842,176 (i8)
static const size_t OFF_S1 = 0;
static const size_t OFF_S2 = OFF_S1 + SZ_S;
static const size_t OFF_B1 = OFF_S2 + SZ_S;                        // 35,684,352
static const size_t OFF_B2 = OFF_B1 + (size_t)NO1 * K1;            // +589,824
static const size_t OFF_C1 = OFF_B2 + (size_t)NO2 * K1;            // +294,912
static const size_t OFF_C2 = OFF_C1 + 1024;
static const size_t OFF_XR = OFF_C2 + 512;                         // ~36.6 MB (256-aligned)

extern "C" void kernel_launch(void* const* d_in, const int* in_sizes, int n_in,
                              void* d_out, int out_size, void* d_ws, size_t ws_size,
                              hipStream_t stream) {
    (void)in_sizes; (void)n_in; (void)out_size; (void)ws_size;
    const float* x      = (const float*)d_in[0];
    const float* w1     = (const float*)d_in[1];
    const float* w2     = (const float*)d_in[2];
    const float* bias1_ = (const float*)d_in[3];
    const float* bias2_ = (const float*)d_in[6];
    const float* bias3  = (const float*)d_in[7];
    const float* bias4  = (const float*)d_in[8];
    const float* ka1    = (const float*)d_in[9];
    const float* kw1    = (const float*)d_in[10];
    const float* ka2    = (const float*)d_in[11];
    const float* kw2    = (const float*)d_in[12];
    const float* slope2 = (const float*)d_in[14];

    char* ws = (char*)d_ws;
    i8*    s1   = (i8*)(ws + OFF_S1);
    i8*    s2   = (i8*)(ws + OFF_S2);
    i8*    Bt1  = (i8*)(ws + OFF_B1);
    i8*    Bt2  = (i8*)(ws + OFF_B2);
    float* sc1  = (float*)(ws + OFF_C1);
    float* sc2  = (float*)(ws + OFF_C2);
    float* xres = (float*)(ws + OFF_XR);
    float* out  = (float*)d_out;

    {
        int total = B_ * PH * PW * (C_ / 16);
        hipLaunchKernelGGL(halo_zero, dim3((total + 255) / 256), dim3(256), 0, stream, s1, s2);
    }
    hipLaunchKernelGGL(prep_s1, dim3(B_ * H_), dim3(256), 0, stream, x, bias1_, s1);
    hipLaunchKernelGGL(prep_w, dim3(NO1 + NO2), dim3(256), 0, stream,
                       w1, w2, ka1, kw1, ka2, kw2, Bt1, Bt2, sc1, sc2);
    hipLaunchKernelGGL((gemm_conv<1>), dim3(1024), dim3(256), 0, stream,
                       s1, Bt1, sc1, x, bias2_, nullptr, nullptr, s2, xres, nullptr);
    hipLaunchKernelGGL((gemm_conv<2>), dim3(512), dim3(256), 0, stream,
                       s2, Bt2, sc2, xres, bias3, bias4, slope2, nullptr, nullptr, out);
}

// Round 7
// 272.536 us; speedup vs baseline: 1.4007x; 1.0210x over previous
//
#include <hip/hip_runtime.h>
#include <hip/hip_bf16.h>
#include <stdint.h>

#define B_   16
#define C_   256
#define H_   64
#define W_   64
#define PH   66
#define PW   66
#define K1   2304   // 256*9
#define NO1  256
#define NO2  128

typedef unsigned short u16;
typedef signed char i8;
typedef int   int32x4 __attribute__((ext_vector_type(4)));

__device__ __forceinline__ void gl_lds16(const void* src, void* dst) {
    __builtin_amdgcn_global_load_lds(
        (const __attribute__((address_space(1))) unsigned int*)src,
        (__attribute__((address_space(3))) unsigned int*)dst, 16, 0, 0);
}

__device__ __forceinline__ i8 sign_i8(float v) {
    return (v > 0.f) ? (i8)1 : ((v < 0.f) ? (i8)(-1) : (i8)0);
}

// ---------------- halo zero: zero the 1-px border of s1 and s2 (i8) -----------
__global__ void halo_zero(i8* __restrict__ s1, i8* __restrict__ s2) {
    int t = blockIdx.x * blockDim.x + threadIdx.x;   // one thread = 16 channels of one pixel
    const int total = B_ * PH * PW * (C_ / 16);
    if (t >= total) return;
    int pix = t >> 4;          // C_/16 = 16 chunks
    int c16 = t & 15;
    int pw  = pix % PW;
    int ph  = (pix / PW) % PH;
    if (ph != 0 && ph != PH - 1 && pw != 0 && pw != PW - 1) return;
    int4 z = make_int4(0, 0, 0, 0);
    *(int4*)(s1 + (size_t)pix * C_ + c16 * 16) = z;
    *(int4*)(s2 + (size_t)pix * C_ + c16 * 16) = z;
}

// ---------------- prep s1: sign(x + bias1_) -> padded NHWC i8 ----------------
__global__ void prep_s1(const float* __restrict__ x, const float* __restrict__ bias1_,
                        i8* __restrict__ s1) {
    __shared__ i8 tile[64][272];           // [w][c], stride 272 (17*16) to spread banks
    int b = blockIdx.x >> 6;
    int h = blockIdx.x & 63;
    int t = threadIdx.x;
    int w  = t & 63;
    int cq = t >> 6;                       // 0..3 (channel quarter)
    for (int i = 0; i < 64; ++i) {
        int c = cq * 64 + i;
        float v = x[((size_t)(b * C_ + c) * H_ + h) * W_ + w] + bias1_[c];
        tile[w][c] = sign_i8(v);
    }
    __syncthreads();
    // write out: 1024 16B-chunks, 4 per thread, consecutive t -> consecutive channels
    for (int i = 0; i < 4; ++i) {
        int idx = i * 256 + t;
        int w2  = idx >> 4;                // 16 chunks per pixel
        int cb  = (idx & 15) * 16;
        int4 v = *(const int4*)&tile[w2][cb];
        *(int4*)(s1 + ((size_t)(b * PH + h + 1) * PW + (w2 + 1)) * C_ + cb) = v;
    }
}

// ---------------- prep weights: scale[o] and sign(w) transposed to [n][k] ------
// k ordering: k = tap*256 + c   (tap = dh*3+dw)
__global__ void prep_w(const float* __restrict__ w1, const float* __restrict__ w2,
                       const float* __restrict__ ka1, const float* __restrict__ kw1,
                       const float* __restrict__ ka2, const float* __restrict__ kw2,
                       i8* __restrict__ Bt1, i8* __restrict__ Bt2,
                       float* __restrict__ scale1, float* __restrict__ scale2) {
    int o = blockIdx.x;
    const float* w; i8* Bt; float* scale; float kk;
    if (o < NO1) { w = w1 + (size_t)o * K1;         Bt = Bt1 + (size_t)o * K1;         scale = scale1 + o;         kk = ka1[0] * kw1[0]; }
    else         { int oo = o - NO1;
                   w = w2 + (size_t)oo * K1;        Bt = Bt2 + (size_t)oo * K1;        scale = scale2 + oo;        kk = ka2[0] * kw2[0]; }
    int t = threadIdx.x;
    float s = 0.f;
    for (int e = t; e < K1; e += 256) {
        float v = w[e];
        s += fabsf(v);
        int c = e / 9, tap = e % 9;
        Bt[tap * 256 + c] = sign_i8(v);
    }
    for (int off = 32; off; off >>= 1) s += __shfl_down(s, off);
    __shared__ float red[4];
    if ((t & 63) == 0) red[t >> 6] = s;
    __syncthreads();
    if (t == 0) {
        float tot = red[0] + red[1] + red[2] + red[3];
        *scale = kk * tot * (1.0f / 2304.0f);
    }
}

// ---------------- implicit-GEMM binary conv, i8, 128x128 tile, BK=128 ----------
// Double-buffered 2-phase pipeline (T3 minimum recipe): stage(t+1) issued before
// compute(t); one trailing {vmcnt(0); s_barrier} per K-step so prefetch latency
// overlaps the whole compute phase. Buffer-reuse safety: all ds_reads of the
// buffer overwritten at step t were consumed by MFMAs before the step t-1
// barrier (compiler's lgkmcnt waits), and vmcnt(0) precedes the barrier.
// T2 XOR swizzle unchanged (linear LDS dst + pre-swizzled global source; read
// side XORs (row&7)<<4). T1 XCD chunk swizzle on the 1D grid.
template<int EPI>
__global__ __launch_bounds__(256)
void gemm_conv(const i8* __restrict__ Sin, const i8* __restrict__ Bt,
               const float* __restrict__ scale,
               const float* __restrict__ xaux,    // EPI1: x (NCHW f32); EPI2: xres_lo (NHWC 128 f32)
               const float* __restrict__ biasA,   // EPI1: bias2_ ; EPI2: bias3
               const float* __restrict__ bias4,   // EPI2 only
               const float* __restrict__ slope,   // EPI2 only
               i8*   __restrict__ s2out,          // EPI1 only
               float* __restrict__ xres_out,      // EPI1 only
               float* __restrict__ dout)          // EPI2 only
{
    __shared__ char lds[64 * 1024];        // 2 x (A 16K + B 16K)

    int t  = threadIdx.x;

    // 1D grid + XCD chunk swizzle (T1): nwg % 8 == 0 -> bijective.
    int wg    = blockIdx.x;
    int chunk = gridDim.x >> 3;
    int logical = (wg & 7) * chunk + (wg >> 3);
    int nb, mb;
    if (EPI == 1) { nb = logical & 1; mb = logical >> 1; }   // nb fastest: A-tile reuse
    else          { nb = 0;           mb = logical; }
    int b  = mb >> 5;
    int h0 = (mb & 31) * 2;        // rows h0, h0+1

    int ar  = t >> 3;              // staging row 0..31 (+i*32); r&7 == (t>>3)&7
    // pre-swizzled global byte offset within the 128B k-row (involution with read side)
    int off = ((t & 7) * 16) ^ (((t >> 3) & 7) << 4);
    int lin = (t & 7) * 16;        // linear LDS dst offset within row

    int l  = t & 63;
    int wv = t >> 6;
    int wr = wv >> 1;              // wave M half
    int wc = wv & 1;               // wave N half

    int32x4 acc[4][4];
#pragma unroll
    for (int mi = 0; mi < 4; ++mi)
#pragma unroll
        for (int ni = 0; ni < 4; ++ni) acc[mi][ni] = (int32x4){0, 0, 0, 0};

    // stage K-step ks into buffer half `sel`
    auto stage = [&](int ks, int sel) {
        char* As = lds + sel * 32768;
        char* Bs = As + 16384;
        int tap = ks >> 1;
        int c0  = (ks & 1) * 128;
        int dh  = tap / 3, dw = tap % 3;
#pragma unroll
        for (int i = 0; i < 4; ++i) {
            int r  = ar + i * 32;
            int hh = r >> 6, ww = r & 63;
            const i8* ga = Sin + ((size_t)(b * PH + h0 + hh + dh) * PW + (ww + dw)) * C_ + c0 + off;
            gl_lds16(ga, As + r * 128 + lin);
        }
#pragma unroll
        for (int i = 0; i < 4; ++i) {
            int r = ar + i * 32;
            int n = nb * 128 + r;
            const i8* gb = Bt + (size_t)n * K1 + tap * 256 + c0 + off;
            gl_lds16(gb, Bs + r * 128 + lin);
        }
    };

    auto compute = [&](int sel) {
        const char* As = lds + sel * 32768;
        const char* Bs = As + 16384;
#pragma unroll
        for (int kk = 0; kk < 2; ++kk) {
            int kb = kk * 64 + ((l >> 4) * 16);   // logical byte offset of this lane's k-group
            int rx = (l & 7) << 4;                // row-dependent xor (row&7 == l&7 here)
            int32x4 af[4], bf[4];
#pragma unroll
            for (int mi = 0; mi < 4; ++mi)
                af[mi] = *(const int32x4*)(As + (wr * 64 + mi * 16 + (l & 15)) * 128 + (kb ^ rx));
#pragma unroll
            for (int ni = 0; ni < 4; ++ni)
                bf[ni] = *(const int32x4*)(Bs + (wc * 64 + ni * 16 + (l & 15)) * 128 + (kb ^ rx));
#pragma unroll
            for (int mi = 0; mi < 4; ++mi)
#pragma unroll
                for (int ni = 0; ni < 4; ++ni)
                    acc[mi][ni] = __builtin_amdgcn_mfma_i32_16x16x64_i8(af[mi], bf[ni], acc[mi][ni], 0, 0, 0);
        }
    };

    // prologue: stage step 0, wait, barrier
    stage(0, 0);
    asm volatile("s_waitcnt vmcnt(0)" ::: "memory");
    __builtin_amdgcn_s_barrier();

    for (int ks = 0; ks < 18; ++ks) {
        int cur = ks & 1;
        if (ks < 17) stage(ks + 1, cur ^ 1);     // prefetch next K-step
        compute(cur);                            // overlaps with prefetch latency
        if (ks < 17) {
            asm volatile("s_waitcnt vmcnt(0)" ::: "memory");
            __builtin_amdgcn_s_barrier();
        }
    }

    // -------- epilogue --------
    int co = l & 15;
    int ro = l >> 4;
#pragma unroll
    for (int mi = 0; mi < 4; ++mi) {
#pragma unroll
        for (int ni = 0; ni < 4; ++ni) {
            int n_loc = wc * 64 + ni * 16 + co;
            int o = nb * 128 + n_loc;
            float sc = scale[o];
#pragma unroll
            for (int j = 0; j < 4; ++j) {
                int m_loc = wr * 64 + mi * 16 + ro * 4 + j;
                int h = h0 + (m_loc >> 6);
                int w = m_loc & 63;
                float v = (float)acc[mi][ni][j] * sc;
                if (EPI == 1) {
                    float xv = xaux[((size_t)(b * C_ + o) * H_ + h) * W_ + w];
                    float xr = v + xv;
                    float sv = xr + biasA[o];
                    s2out[((size_t)(b * PH + h + 1) * PW + (w + 1)) * C_ + o] = sign_i8(sv);
                    if (o < NO2)
                        xres_out[(((size_t)b * H_ + h) * W_ + w) * NO2 + o] = xr;
                } else {
                    float xr = xaux[(((size_t)b * H_ + h) * W_ + w) * NO2 + o];
                    float vv = v + xr + biasA[o];
                    vv = (vv >= 0.f) ? vv : vv * slope[o];
                    vv += bias4[o];
                    int p = h & 1, q = w & 1;
                    dout[(((size_t)b * 512 + (o * 4 + p * 2 + q)) * 32 + (h >> 1)) * 32 + (w >> 1)] = vv;
                }
            }
        }
    }
}

// ---------------- workspace layout (bytes, 256-aligned) ----------------
static const size_t SZ_S   = (size_t)B_ * PH * PW * C_;           // 17,842,176 (i8)
static const size_t OFF_S1 = 0;
static const size_t OFF_S2 = OFF_S1 + SZ_S;
static const size_t OFF_B1 = OFF_S2 + SZ_S;                        // 35,684,352
static const size_t OFF_B2 = OFF_B1 + (size_t)NO1 * K1;            // +589,824
static const size_t OFF_C1 = OFF_B2 + (size_t)NO2 * K1;            // +294,912
static const size_t OFF_C2 = OFF_C1 + 1024;
static const size_t OFF_XR = OFF_C2 + 512;                         // ~36.6 MB (256-aligned)

extern "C" void kernel_launch(void* const* d_in, const int* in_sizes, int n_in,
                              void* d_out, int out_size, void* d_ws, size_t ws_size,
                              hipStream_t stream) {
    (void)in_sizes; (void)n_in; (void)out_size; (void)ws_size;
    const float* x      = (const float*)d_in[0];
    const float* w1     = (const float*)d_in[1];
    const float* w2     = (const float*)d_in[2];
    const float* bias1_ = (const float*)d_in[3];
    const float* bias2_ = (const float*)d_in[6];
    const float* bias3  = (const float*)d_in[7];
    const float* bias4  = (const float*)d_in[8];
    const float* ka1    = (const float*)d_in[9];
    const float* kw1    = (const float*)d_in[10];
    const float* ka2    = (const float*)d_in[11];
    const float* kw2    = (const float*)d_in[12];
    const float* slope2 = (const float*)d_in[14];

    char* ws = (char*)d_ws;
    i8*    s1   = (i8*)(ws + OFF_S1);
    i8*    s2   = (i8*)(ws + OFF_S2);
    i8*    Bt1  = (i8*)(ws + OFF_B1);
    i8*    Bt2  = (i8*)(ws + OFF_B2);
    float* sc1  = (float*)(ws + OFF_C1);
    float* sc2  = (float*)(ws + OFF_C2);
    float* xres = (float*)(ws + OFF_XR);
    float* out  = (float*)d_out;

    {
        int total = B_ * PH * PW * (C_ / 16);
        hipLaunchKernelGGL(halo_zero, dim3((total + 255) / 256), dim3(256), 0, stream, s1, s2);
    }
    hipLaunchKernelGGL(prep_s1, dim3(B_ * H_), dim3(256), 0, stream, x, bias1_, s1);
    hipLaunchKernelGGL(prep_w, dim3(NO1 + NO2), dim3(256), 0, stream,
                       w1, w2, ka1, kw1, ka2, kw2, Bt1, Bt2, sc1, sc2);
    hipLaunchKernelGGL((gemm_conv<1>), dim3(1024), dim3(256), 0, stream,
                       s1, Bt1, sc1, x, bias2_, nullptr, nullptr, s2, xres, nullptr);
    hipLaunchKernelGGL((gemm_conv<2>), dim3(512), dim3(256), 0, stream,
                       s2, Bt2, sc2, xres, bias3, bias4, slope2, nullptr, nullptr, out);
}

// Round 8
// 267.613 us; speedup vs baseline: 1.4265x; 1.0184x over previous
//
#include <hip/hip_runtime.h>
#include <hip/hip_bf16.h>
#include <stdint.h>

#define B_   16
#define C_   256
#define H_   64
#define W_   64
#define PH   66
#define PW   66
#define K1   2304   // 256*9
#define NO1  256
#define NO2  128

typedef signed char i8;
typedef int   int32x4 __attribute__((ext_vector_type(4)));

__device__ __forceinline__ void gl_lds16(const void* src, void* dst) {
    __builtin_amdgcn_global_load_lds(
        (const __attribute__((address_space(1))) unsigned int*)src,
        (__attribute__((address_space(3))) unsigned int*)dst, 16, 0, 0);
}

__device__ __forceinline__ i8 sign_i8(float v) {
    return (v > 0.f) ? (i8)1 : ((v < 0.f) ? (i8)(-1) : (i8)0);
}

// ---------------- halo zero: zero the 1-px border of s1 and s2 (i8) -----------
__global__ void halo_zero(i8* __restrict__ s1, i8* __restrict__ s2) {
    int t = blockIdx.x * blockDim.x + threadIdx.x;   // one thread = 16 channels of one pixel
    const int total = B_ * PH * PW * (C_ / 16);
    if (t >= total) return;
    int pix = t >> 4;          // C_/16 = 16 chunks
    int c16 = t & 15;
    int pw  = pix % PW;
    int ph  = (pix / PW) % PH;
    if (ph != 0 && ph != PH - 1 && pw != 0 && pw != PW - 1) return;
    int4 z = make_int4(0, 0, 0, 0);
    *(int4*)(s1 + (size_t)pix * C_ + c16 * 16) = z;
    *(int4*)(s2 + (size_t)pix * C_ + c16 * 16) = z;
}

// ---------------- prep s1: sign(x + bias1_) -> padded NHWC i8 ----------------
__global__ void prep_s1(const float* __restrict__ x, const float* __restrict__ bias1_,
                        i8* __restrict__ s1) {
    __shared__ i8 tile[64][272];           // [w][c], stride 272 (17*16) to spread banks
    int b = blockIdx.x >> 6;
    int h = blockIdx.x & 63;
    int t = threadIdx.x;
    int w  = t & 63;
    int cq = t >> 6;                       // 0..3 (channel quarter)
    for (int i = 0; i < 64; ++i) {
        int c = cq * 64 + i;
        float v = x[((size_t)(b * C_ + c) * H_ + h) * W_ + w] + bias1_[c];
        tile[w][c] = sign_i8(v);
    }
    __syncthreads();
    // write out: 1024 16B-chunks, 4 per thread, consecutive t -> consecutive channels
    for (int i = 0; i < 4; ++i) {
        int idx = i * 256 + t;
        int w2  = idx >> 4;                // 16 chunks per pixel
        int cb  = (idx & 15) * 16;
        int4 v = *(const int4*)&tile[w2][cb];
        *(int4*)(s1 + ((size_t)(b * PH + h + 1) * PW + (w2 + 1)) * C_ + cb) = v;
    }
}

// ---------------- prep weights: scale[o] and sign(w) transposed to [n][k] ------
// k ordering: k = tap*256 + c   (tap = dh*3+dw)
__global__ void prep_w(const float* __restrict__ w1, const float* __restrict__ w2,
                       const float* __restrict__ ka1, const float* __restrict__ kw1,
                       const float* __restrict__ ka2, const float* __restrict__ kw2,
                       i8* __restrict__ Bt1, i8* __restrict__ Bt2,
                       float* __restrict__ scale1, float* __restrict__ scale2) {
    int o = blockIdx.x;
    const float* w; i8* Bt; float* scale; float kk;
    if (o < NO1) { w = w1 + (size_t)o * K1;         Bt = Bt1 + (size_t)o * K1;         scale = scale1 + o;         kk = ka1[0] * kw1[0]; }
    else         { int oo = o - NO1;
                   w = w2 + (size_t)oo * K1;        Bt = Bt2 + (size_t)oo * K1;        scale = scale2 + oo;        kk = ka2[0] * kw2[0]; }
    int t = threadIdx.x;
    float s = 0.f;
    for (int e = t; e < K1; e += 256) {
        float v = w[e];
        s += fabsf(v);
        int c = e / 9, tap = e % 9;
        Bt[tap * 256 + c] = sign_i8(v);
    }
    for (int off = 32; off; off >>= 1) s += __shfl_down(s, off);
    __shared__ float red[4];
    if ((t & 63) == 0) red[t >> 6] = s;
    __syncthreads();
    if (t == 0) {
        float tot = red[0] + red[1] + red[2] + red[3];
        *scale = kk * tot * (1.0f / 2304.0f);
    }
}

// ---------------- implicit-GEMM binary conv, i8, 256x128 tile, BK=128 ----------
// Depth-2 pipeline, 3 LDS buffers, COUNTED vmcnt (T3+T4): iter ks issues
// stage(ks+2), computes buf cur, then waits vmcnt(6) (= step ks+1's 6 loads;
// step ks+2's 6 stay in flight across the barrier — never drains to 0 in the
// main loop). Safety: buffer written at ks was last read at compute(ks-3)...
// concretely stage(ks+2)->buf that compute(ks-1) read; its ds_reads completed
// before the ks-1 barrier (lgkmcnt before MFMAs). vmcnt(6) before barrier
// guarantees buf(ks+1) is fully landed when any wave enters compute(ks+1).
// T2 XOR swizzle (linear LDS dst + pre-swizzled global source; read XORs
// (row&7)<<4). T1 XCD chunk swizzle. T5 setprio around MFMA cluster.
template<int EPI>
__global__ __launch_bounds__(512)
void gemm_conv(const i8* __restrict__ Sin, const i8* __restrict__ Bt,
               const float* __restrict__ scale,
               const float* __restrict__ xaux,    // EPI1: x (NCHW f32); EPI2: xres_lo (NHWC 128 f32)
               const float* __restrict__ biasA,   // EPI1: bias2_ ; EPI2: bias3
               const float* __restrict__ bias4,   // EPI2 only
               const float* __restrict__ slope,   // EPI2 only
               i8*   __restrict__ s2out,          // EPI1 only
               float* __restrict__ xres_out,      // EPI1 only
               float* __restrict__ dout)          // EPI2 only
{
    extern __shared__ char lds[];          // 3 x (A 32K + B 16K) = 144 KB

    int t  = threadIdx.x;

    // 1D grid + XCD chunk swizzle (T1): nwg % 8 == 0 -> bijective.
    int wg    = blockIdx.x;
    int chunk = gridDim.x >> 3;
    int logical = (wg & 7) * chunk + (wg >> 3);
    int nb, mb;
    if (EPI == 1) { nb = logical & 1; mb = logical >> 1; }   // nb fastest: A-tile reuse
    else          { nb = 0;           mb = logical; }
    int b  = mb >> 4;
    int h0 = (mb & 15) * 4;        // rows h0..h0+3

    // staging: 512 threads; A-tile 256x128B (4 chunks/thread), B-tile 128x128B (2)
    int r0  = t >> 3;              // 0..63; r&7 == (t>>3)&7 for all i*64 strides
    int off = ((t & 7) * 16) ^ (((t >> 3) & 7) << 4);  // pre-swizzled global byte offset
    int lin = (t & 7) * 16;        // linear LDS dst offset within 128B row

    int l  = t & 63;
    int wv = t >> 6;               // 0..7
    int wr = wv >> 1;              // 0..3 : wave M quarter
    int wc = wv & 1;               // 0..1 : wave N half

    int32x4 acc[4][4];
#pragma unroll
    for (int mi = 0; mi < 4; ++mi)
#pragma unroll
        for (int ni = 0; ni < 4; ++ni) acc[mi][ni] = (int32x4){0, 0, 0, 0};

    auto stage = [&](int ks, char* buf) {
        char* As = buf;                    // [256 rows][128B]
        char* Bs = buf + 32768;            // [128 rows][128B]
        int tap = ks >> 1;
        int c0  = (ks & 1) * 128;
        int dh  = tap / 3, dw = tap % 3;
#pragma unroll
        for (int i = 0; i < 4; ++i) {
            int r  = r0 + i * 64;          // 0..255
            int hh = r >> 6, ww = r & 63;
            const i8* ga = Sin + ((size_t)(b * PH + h0 + hh + dh) * PW + (ww + dw)) * C_ + c0 + off;
            gl_lds16(ga, As + r * 128 + lin);
        }
#pragma unroll
        for (int i = 0; i < 2; ++i) {
            int r = r0 + i * 64;           // 0..127
            int n = nb * 128 + r;
            const i8* gb = Bt + (size_t)n * K1 + tap * 256 + c0 + off;
            gl_lds16(gb, Bs + r * 128 + lin);
        }
    };

    auto compute = [&](const char* buf) {
        const char* As = buf;
        const char* Bs = buf + 32768;
        __builtin_amdgcn_s_setprio(1);
#pragma unroll
        for (int kk = 0; kk < 2; ++kk) {
            int kb = kk * 64 + ((l >> 4) * 16);   // logical byte offset of lane's k-group
            int rx = (l & 7) << 4;                // row-dependent xor (row&7 == l&7 here)
            int32x4 af[4], bf[4];
#pragma unroll
            for (int mi = 0; mi < 4; ++mi)
                af[mi] = *(const int32x4*)(As + (wr * 64 + mi * 16 + (l & 15)) * 128 + (kb ^ rx));
#pragma unroll
            for (int ni = 0; ni < 4; ++ni)
                bf[ni] = *(const int32x4*)(Bs + (wc * 64 + ni * 16 + (l & 15)) * 128 + (kb ^ rx));
#pragma unroll
            for (int mi = 0; mi < 4; ++mi)
#pragma unroll
                for (int ni = 0; ni < 4; ++ni)
                    acc[mi][ni] = __builtin_amdgcn_mfma_i32_16x16x64_i8(af[mi], bf[ni], acc[mi][ni], 0, 0, 0);
        }
        __builtin_amdgcn_s_setprio(0);
    };

    char* bc  = lds;                       // current
    char* bn  = lds + 49152;               // next
    char* bn2 = lds + 98304;               // next-next

    // prologue: 12 loads in flight; wait the older 6 (step 0)
    stage(0, bc);
    stage(1, bn);
    asm volatile("s_waitcnt vmcnt(6)" ::: "memory");
    __builtin_amdgcn_s_barrier();

    for (int ks = 0; ks < 18; ++ks) {
        if (ks < 16) stage(ks + 2, bn2);   // 6 more loads -> 12 outstanding
        compute(bc);
        if (ks < 16)      asm volatile("s_waitcnt vmcnt(6)" ::: "memory");  // ks+1 landed; ks+2 in flight
        else if (ks == 16) asm volatile("s_waitcnt vmcnt(0)" ::: "memory"); // drain for last step
        if (ks < 17) __builtin_amdgcn_s_barrier();
        char* tmp = bc; bc = bn; bn = bn2; bn2 = tmp;   // rotate (no runtime indexing)
    }

    // -------- epilogue --------
    int co = l & 15;
    int ro = l >> 4;
#pragma unroll
    for (int mi = 0; mi < 4; ++mi) {
#pragma unroll
        for (int ni = 0; ni < 4; ++ni) {
            int n_loc = wc * 64 + ni * 16 + co;
            int o = nb * 128 + n_loc;
            float sc = scale[o];
#pragma unroll
            for (int j = 0; j < 4; ++j) {
                int m_loc = wr * 64 + mi * 16 + ro * 4 + j;
                int h = h0 + (m_loc >> 6);
                int w = m_loc & 63;
                float v = (float)acc[mi][ni][j] * sc;
                if (EPI == 1) {
                    float xv = xaux[((size_t)(b * C_ + o) * H_ + h) * W_ + w];
                    float xr = v + xv;
                    float sv = xr + biasA[o];
                    s2out[((size_t)(b * PH + h + 1) * PW + (w + 1)) * C_ + o] = sign_i8(sv);
                    if (o < NO2)
                        xres_out[(((size_t)b * H_ + h) * W_ + w) * NO2 + o] = xr;
                } else {
                    float xr = xaux[(((size_t)b * H_ + h) * W_ + w) * NO2 + o];
                    float vv = v + xr + biasA[o];
                    vv = (vv >= 0.f) ? vv : vv * slope[o];
                    vv += bias4[o];
                    int p = h & 1, q = w & 1;
                    dout[(((size_t)b * 512 + (o * 4 + p * 2 + q)) * 32 + (h >> 1)) * 32 + (w >> 1)] = vv;
                }
            }
        }
    }
}

// ---------------- workspace layout (bytes, 256-aligned) ----------------
static const size_t SZ_S   = (size_t)B_ * PH * PW * C_;           // 17,842,176 (i8)
static const size_t OFF_S1 = 0;
static const size_t OFF_S2 = OFF_S1 + SZ_S;
static const size_t OFF_B1 = OFF_S2 + SZ_S;                        // 35,684,352
static const size_t OFF_B2 = OFF_B1 + (size_t)NO1 * K1;            // +589,824
static const size_t OFF_C1 = OFF_B2 + (size_t)NO2 * K1;            // +294,912
static const size_t OFF_C2 = OFF_C1 + 1024;
static const size_t OFF_XR = OFF_C2 + 512;                         // ~36.6 MB (256-aligned)

extern "C" void kernel_launch(void* const* d_in, const int* in_sizes, int n_in,
                              void* d_out, int out_size, void* d_ws, size_t ws_size,
                              hipStream_t stream) {
    (void)in_sizes; (void)n_in; (void)out_size; (void)ws_size;
    const float* x      = (const float*)d_in[0];
    const float* w1     = (const float*)d_in[1];
    const float* w2     = (const float*)d_in[2];
    const float* bias1_ = (const float*)d_in[3];
    const float* bias2_ = (const float*)d_in[6];
    const float* bias3  = (const float*)d_in[7];
    const float* bias4  = (const float*)d_in[8];
    const float* ka1    = (const float*)d_in[9];
    const float* kw1    = (const float*)d_in[10];
    const float* ka2    = (const float*)d_in[11];
    const float* kw2    = (const float*)d_in[12];
    const float* slope2 = (const float*)d_in[14];

    char* ws = (char*)d_ws;
    i8*    s1   = (i8*)(ws + OFF_S1);
    i8*    s2   = (i8*)(ws + OFF_S2);
    i8*    Bt1  = (i8*)(ws + OFF_B1);
    i8*    Bt2  = (i8*)(ws + OFF_B2);
    float* sc1  = (float*)(ws + OFF_C1);
    float* sc2  = (float*)(ws + OFF_C2);
    float* xres = (float*)(ws + OFF_XR);
    float* out  = (float*)d_out;

    {
        int total = B_ * PH * PW * (C_ / 16);
        hipLaunchKernelGGL(halo_zero, dim3((total + 255) / 256), dim3(256), 0, stream, s1, s2);
    }
    hipLaunchKernelGGL(prep_s1, dim3(B_ * H_), dim3(256), 0, stream, x, bias1_, s1);
    hipLaunchKernelGGL(prep_w, dim3(NO1 + NO2), dim3(256), 0, stream,
                       w1, w2, ka1, kw1, ka2, kw2, Bt1, Bt2, sc1, sc2);
    hipLaunchKernelGGL((gemm_conv<1>), dim3(512), dim3(512), 147456, stream,
                       s1, Bt1, sc1, x, bias2_, nullptr, nullptr, s2, xres, nullptr);
    hipLaunchKernelGGL((gemm_conv<2>), dim3(256), dim3(512), 147456, stream,
                       s2, Bt2, sc2, xres, bias3, bias4, slope2, nullptr, nullptr, out);
}

// Round 9
// 266.793 us; speedup vs baseline: 1.4309x; 1.0031x over previous
//
#include <hip/hip_runtime.h>
#include <hip/hip_bf16.h>
#include <stdint.h>

#define B_   16
#define C_   256
#define H_   64
#define W_   64
#define PH   66
#define PW   66
#define K1   2304   // 256*9
#define NO1  256
#define NO2  128

typedef signed char i8;
typedef int   int32x4 __attribute__((ext_vector_type(4)));

__device__ __forceinline__ void gl_lds16(const void* src, void* dst) {
    __builtin_amdgcn_global_load_lds(
        (const __attribute__((address_space(1))) unsigned int*)src,
        (__attribute__((address_space(3))) unsigned int*)dst, 16, 0, 0);
}

__device__ __forceinline__ i8 sign_i8(float v) {
    return (v > 0.f) ? (i8)1 : ((v < 0.f) ? (i8)(-1) : (i8)0);
}

// ---------------- halo zero: zero the 1-px border of s1 and s2 (i8) -----------
__global__ void halo_zero(i8* __restrict__ s1, i8* __restrict__ s2) {
    int t = blockIdx.x * blockDim.x + threadIdx.x;   // one thread = 16 channels of one pixel
    const int total = B_ * PH * PW * (C_ / 16);
    if (t >= total) return;
    int pix = t >> 4;          // C_/16 = 16 chunks
    int c16 = t & 15;
    int pw  = pix % PW;
    int ph  = (pix / PW) % PH;
    if (ph != 0 && ph != PH - 1 && pw != 0 && pw != PW - 1) return;
    int4 z = make_int4(0, 0, 0, 0);
    *(int4*)(s1 + (size_t)pix * C_ + c16 * 16) = z;
    *(int4*)(s2 + (size_t)pix * C_ + c16 * 16) = z;
}

// ---------------- prep s1: sign(x + bias1_) -> padded NHWC i8 ----------------
__global__ void prep_s1(const float* __restrict__ x, const float* __restrict__ bias1_,
                        i8* __restrict__ s1) {
    __shared__ i8 tile[64][272];           // [w][c], stride 272 (17*16) to spread banks
    int b = blockIdx.x >> 6;
    int h = blockIdx.x & 63;
    int t = threadIdx.x;
    int w  = t & 63;
    int cq = t >> 6;                       // 0..3 (channel quarter)
    for (int i = 0; i < 64; ++i) {
        int c = cq * 64 + i;
        float v = x[((size_t)(b * C_ + c) * H_ + h) * W_ + w] + bias1_[c];
        tile[w][c] = sign_i8(v);
    }
    __syncthreads();
    for (int i = 0; i < 4; ++i) {
        int idx = i * 256 + t;
        int w2  = idx >> 4;                // 16 chunks per pixel
        int cb  = (idx & 15) * 16;
        int4 v = *(const int4*)&tile[w2][cb];
        *(int4*)(s1 + ((size_t)(b * PH + h + 1) * PW + (w2 + 1)) * C_ + cb) = v;
    }
}

// ---------------- prep weights: scale[o] and sign(w) transposed to [n][k] ------
// k ordering: k = tap*256 + c   (tap = dh*3+dw)
__global__ void prep_w(const float* __restrict__ w1, const float* __restrict__ w2,
                       const float* __restrict__ ka1, const float* __restrict__ kw1,
                       const float* __restrict__ ka2, const float* __restrict__ kw2,
                       i8* __restrict__ Bt1, i8* __restrict__ Bt2,
                       float* __restrict__ scale1, float* __restrict__ scale2) {
    int o = blockIdx.x;
    const float* w; i8* Bt; float* scale; float kk;
    if (o < NO1) { w = w1 + (size_t)o * K1;         Bt = Bt1 + (size_t)o * K1;         scale = scale1 + o;         kk = ka1[0] * kw1[0]; }
    else         { int oo = o - NO1;
                   w = w2 + (size_t)oo * K1;        Bt = Bt2 + (size_t)oo * K1;        scale = scale2 + oo;        kk = ka2[0] * kw2[0]; }
    int t = threadIdx.x;
    float s = 0.f;
    for (int e = t; e < K1; e += 256) {
        float v = w[e];
        s += fabsf(v);
        int c = e / 9, tap = e % 9;
        Bt[tap * 256 + c] = sign_i8(v);
    }
    for (int off = 32; off; off >>= 1) s += __shfl_down(s, off);
    __shared__ float red[4];
    if ((t & 63) == 0) red[t >> 6] = s;
    __syncthreads();
    if (t == 0) {
        float tot = red[0] + red[1] + red[2] + red[3];
        *scale = kk * tot * (1.0f / 2304.0f);
    }
}

// ---------------- A-resident implicit-GEMM binary conv ------------------------
// Block tile: BM=256 output rows (b, h0..h0+3, all 64 w), BN=128 cols, K=2304.
// KEY CHANGE vs R8: the block's ENTIRE A-footprint (6 padded rows x 66 cols x
// 256 ch = 101 KB i8) is staged ONCE in the prologue; the 18 K-steps (9 taps x
// 2 ch-halves) read it with tap-shifted LDS addresses — no per-step A staging,
// no A hazards, no VMEM drain in the loop. Only B (16 KB/step) is staged,
// triple-buffered with counted vmcnt(2) (depth-2, never drains to 0 mid-loop).
// A swizzle: LDS[pix][slot] holds global chunk (slot ^ (pix&7)) — stage-source
// and read use the same involution (rule #21). B swizzle as before.
template<int EPI>
__device__ __forceinline__ void conv_body(
               char* lds,
               const i8* __restrict__ Sin, const i8* __restrict__ Bt,
               const float* __restrict__ scale,
               const float* __restrict__ xaux,    // EPI1: x (NCHW f32); EPI2: xres_lo (NHWC 128 f32)
               const float* __restrict__ biasA,   // EPI1: bias2_ ; EPI2: bias3
               const float* __restrict__ bias4,   // EPI2 only
               const float* __restrict__ slope,   // EPI2 only
               i8*   __restrict__ s2out,          // EPI1 only
               float* __restrict__ xres_out,      // EPI1 only
               float* __restrict__ dout)          // EPI2 only
{
    char* Alds = lds;                      // 6*66 pixel-rows x 256 B = 101376
    char* Bs0  = lds + 101376;             // 3 B-slots x (128 rows x 128 B)
    char* Bs1  = Bs0 + 16384;
    char* Bs2  = Bs1 + 16384;

    int t  = threadIdx.x;

    // 1D grid + XCD chunk swizzle (T1): nwg % 8 == 0 -> bijective.
    int wg    = blockIdx.x;
    int chunk = gridDim.x >> 3;
    int logical = (wg & 7) * chunk + (wg >> 3);
    int nb, mb;
    if (EPI == 1) { nb = logical & 1; mb = logical >> 1; }   // nb pair shares A (L2-adjacent)
    else          { nb = 0;           mb = logical; }
    int b  = mb >> 4;
    int h0 = (mb & 15) * 4;        // output rows h0..h0+3

    int l  = t & 63;
    int wv = t >> 6;               // 0..7
    int wr = wv >> 1;              // 0..3 : wave M quarter (64 rows)
    int wc = wv & 1;               // 0..1 : wave N half   (64 cols)

    // ---- B staging (same verified pattern as R8) ----
    int br0  = t >> 3;                                     // row 0..63 (+64)
    int bsrc = ((t & 7) * 16) ^ (((t >> 3) & 7) << 4);     // pre-swizzled source byte
    int blin = (t & 7) * 16;                               // linear LDS dst byte

    auto stageB = [&](int ks, char* Bs) {
        int tap = ks >> 1;
        int c0  = (ks & 1) * 128;
#pragma unroll
        for (int i = 0; i < 2; ++i) {
            int r = br0 + i * 64;
            int n = nb * 128 + r;
            const i8* gb = Bt + (size_t)n * K1 + tap * 256 + c0 + bsrc;
            gl_lds16(gb, Bs + r * 128 + blin);
        }
    };

    // ---- prologue: B(0), B(1), then the whole A tile (6336 x 16B chunks) ----
    stageB(0, Bs0);
    stageB(1, Bs1);
    for (int i = 0; i < 13; ++i) {
        int idx = i * 512 + t;
        if (idx < 6336) {
            int r6   = idx / 1056;             // padded row 0..5
            int rem  = idx - r6 * 1056;
            int w66  = rem >> 4;               // padded col 0..65
            int slot = rem & 15;
            int pix  = r6 * 66 + w66;
            const i8* ga = Sin + ((size_t)(b * PH + h0 + r6) * PW + w66) * 256
                               + ((slot ^ (pix & 7)) << 4);
            gl_lds16(ga, Alds + idx * 16);     // dst is linear: idx*16 == pix*256+slot*16
        }
    }
    asm volatile("s_waitcnt vmcnt(0)" ::: "memory");
    __builtin_amdgcn_s_barrier();

    // ---- per-thread constants ----
    int q = l >> 4;                            // 0..3 : 16B slot within 64B k-group
    int pixbase[4];
#pragma unroll
    for (int mi = 0; mi < 4; ++mi) {
        int m = wr * 64 + mi * 16 + (l & 15);  // block row 0..255
        pixbase[mi] = (m >> 6) * 66 + (m & 63);
    }
    int rx = (l & 7) << 4;
    int bfbase[4];
#pragma unroll
    for (int ni = 0; ni < 4; ++ni)
        bfbase[ni] = (wc * 64 + ni * 16 + (l & 15)) * 128;
    int bfoff[2] = { (q * 16) ^ rx, (64 + q * 16) ^ rx };

    int32x4 acc[4][4];
#pragma unroll
    for (int mi = 0; mi < 4; ++mi)
#pragma unroll
        for (int ni = 0; ni < 4; ++ni) acc[mi][ni] = (int32x4){0, 0, 0, 0};

    char* pr = Bs0; char* pn = Bs1; char* ps = Bs2;

    for (int ks = 0; ks < 18; ++ks) {
        if (ks < 16) stageB(ks + 2, ps);       // depth-2 B prefetch
        {
            int tap  = ks >> 1;
            int toff = (tap / 3) * 66 + (tap % 3);   // dh*66 + dw
            int c8   = (ks & 1) << 7;                // 0 or 128
            __builtin_amdgcn_s_setprio(1);
#pragma unroll
            for (int kk = 0; kk < 2; ++kk) {
                int qk = kk * 4 + q;
                int32x4 af[4], bf[4];
#pragma unroll
                for (int mi = 0; mi < 4; ++mi) {
                    int pixm = pixbase[mi] + toff;
                    int addr = pixm * 256 + c8 + ((qk ^ (pixm & 7)) << 4);
                    af[mi] = *(const int32x4*)(Alds + addr);
                }
#pragma unroll
                for (int ni = 0; ni < 4; ++ni)
                    bf[ni] = *(const int32x4*)(pr + bfbase[ni] + bfoff[kk]);
#pragma unroll
                for (int mi = 0; mi < 4; ++mi)
#pragma unroll
                    for (int ni = 0; ni < 4; ++ni)
                        acc[mi][ni] = __builtin_amdgcn_mfma_i32_16x16x64_i8(af[mi], bf[ni], acc[mi][ni], 0, 0, 0);
            }
            __builtin_amdgcn_s_setprio(0);
        }
        if (ks < 16)      asm volatile("s_waitcnt vmcnt(2)" ::: "memory");  // B(ks+1) landed
        else if (ks == 16) asm volatile("s_waitcnt vmcnt(0)" ::: "memory");
        if (ks < 17) __builtin_amdgcn_s_barrier();
        char* tmp = pr; pr = pn; pn = ps; ps = tmp;    // manual 3-rotation (rule #20)
    }

    // -------- epilogue (unchanged) --------
    int co = l & 15;
    int ro = l >> 4;
#pragma unroll
    for (int mi = 0; mi < 4; ++mi) {
#pragma unroll
        for (int ni = 0; ni < 4; ++ni) {
            int n_loc = wc * 64 + ni * 16 + co;
            int o = nb * 128 + n_loc;
            float sc = scale[o];
#pragma unroll
            for (int j = 0; j < 4; ++j) {
                int m_loc = wr * 64 + mi * 16 + ro * 4 + j;
                int h = h0 + (m_loc >> 6);
                int w = m_loc & 63;
                float v = (float)acc[mi][ni][j] * sc;
                if (EPI == 1) {
                    float xv = xaux[((size_t)(b * C_ + o) * H_ + h) * W_ + w];
                    float xr = v + xv;
                    float sv = xr + biasA[o];
                    s2out[((size_t)(b * PH + h + 1) * PW + (w + 1)) * C_ + o] = sign_i8(sv);
                    if (o < NO2)
                        xres_out[(((size_t)b * H_ + h) * W_ + w) * NO2 + o] = xr;
                } else {
                    float xr = xaux[(((size_t)b * H_ + h) * W_ + w) * NO2 + o];
                    float vv = v + xr + biasA[o];
                    vv = (vv >= 0.f) ? vv : vv * slope[o];
                    vv += bias4[o];
                    int p = h & 1, qq = w & 1;
                    dout[(((size_t)b * 512 + (o * 4 + p * 2 + qq)) * 32 + (h >> 1)) * 32 + (w >> 1)] = vv;
                }
            }
        }
    }
}

// distinct names so rocprof disaggregates conv1 vs conv2
__global__ __launch_bounds__(512) void conv_g1(
    const i8* Sin, const i8* Bt, const float* scale, const float* xaux,
    const float* biasA, const float* bias4, const float* slope,
    i8* s2out, float* xres_out, float* dout) {
    extern __shared__ char lds[];
    conv_body<1>(lds, Sin, Bt, scale, xaux, biasA, bias4, slope, s2out, xres_out, dout);
}
__global__ __launch_bounds__(512) void conv_g2(
    const i8* Sin, const i8* Bt, const float* scale, const float* xaux,
    const float* biasA, const float* bias4, const float* slope,
    i8* s2out, float* xres_out, float* dout) {
    extern __shared__ char lds[];
    conv_body<2>(lds, Sin, Bt, scale, xaux, biasA, bias4, slope, s2out, xres_out, dout);
}

// ---------------- workspace layout (bytes, 256-aligned) ----------------
static const size_t SZ_S   = (size_t)B_ * PH * PW * C_;           // 17,842,176 (i8)
static const size_t OFF_S1 = 0;
static const size_t OFF_S2 = OFF_S1 + SZ_S;
static const size_t OFF_B1 = OFF_S2 + SZ_S;                        // 35,684,352
static const size_t OFF_B2 = OFF_B1 + (size_t)NO1 * K1;            // +589,824
static const size_t OFF_C1 = OFF_B2 + (size_t)NO2 * K1;            // +294,912
static const size_t OFF_C2 = OFF_C1 + 1024;
static const size_t OFF_XR = OFF_C2 + 512;                         // ~36.6 MB (256-aligned)

static const int LDS_BYTES = 101376 + 3 * 16384;                   // 150,528

extern "C" void kernel_launch(void* const* d_in, const int* in_sizes, int n_in,
                              void* d_out, int out_size, void* d_ws, size_t ws_size,
                              hipStream_t stream) {
    (void)in_sizes; (void)n_in; (void)out_size; (void)ws_size;
    const float* x      = (const float*)d_in[0];
    const float* w1     = (const float*)d_in[1];
    const float* w2     = (const float*)d_in[2];
    const float* bias1_ = (const float*)d_in[3];
    const float* bias2_ = (const float*)d_in[6];
    const float* bias3  = (const float*)d_in[7];
    const float* bias4  = (const float*)d_in[8];
    const float* ka1    = (const float*)d_in[9];
    const float* kw1    = (const float*)d_in[10];
    const float* ka2    = (const float*)d_in[11];
    const float* kw2    = (const float*)d_in[12];
    const float* slope2 = (const float*)d_in[14];

    char* ws = (char*)d_ws;
    i8*    s1   = (i8*)(ws + OFF_S1);
    i8*    s2   = (i8*)(ws + OFF_S2);
    i8*    Bt1  = (i8*)(ws + OFF_B1);
    i8*    Bt2  = (i8*)(ws + OFF_B2);
    float* sc1  = (float*)(ws + OFF_C1);
    float* sc2  = (float*)(ws + OFF_C2);
    float* xres = (float*)(ws + OFF_XR);
    float* out  = (float*)d_out;

    {
        int total = B_ * PH * PW * (C_ / 16);
        hipLaunchKernelGGL(halo_zero, dim3((total + 255) / 256), dim3(256), 0, stream, s1, s2);
    }
    hipLaunchKernelGGL(prep_s1, dim3(B_ * H_), dim3(256), 0, stream, x, bias1_, s1);
    hipLaunchKernelGGL(prep_w, dim3(NO1 + NO2), dim3(256), 0, stream,
                       w1, w2, ka1, kw1, ka2, kw2, Bt1, Bt2, sc1, sc2);
    hipLaunchKernelGGL(conv_g1, dim3(512), dim3(512), LDS_BYTES, stream,
                       s1, Bt1, sc1, x, bias2_, nullptr, nullptr, s2, xres, nullptr);
    hipLaunchKernelGGL(conv_g2, dim3(256), dim3(512), LDS_BYTES, stream,
                       s2, Bt2, sc2, xres, bias3, bias4, slope2, nullptr, nullptr, out);
}